// Round 10
// baseline (448.355 us; speedup 1.0000x reference)
//
#include <hip/hip_runtime.h>
#include <hip/hip_bf16.h>
#include <math.h>

typedef __hip_bfloat16 bf16;

#define B 2
#define L 2048
#define DM 768
#define NH 12
#define DH 64
#define DFF 2304
#define M_TOK (B * L) // 4096

typedef __attribute__((ext_vector_type(8))) short bfrag;
typedef __attribute__((ext_vector_type(4))) float ffrag;
typedef __attribute__((ext_vector_type(16))) float facc16;

__device__ __forceinline__ float waveSum(float v) {
#pragma unroll
  for (int o = 32; o > 0; o >>= 1) v += __shfl_down(v, o, 64);
  return v;
}

__device__ __forceinline__ void gld16(void* l, const void* g) {
  __builtin_amdgcn_global_load_lds((const __attribute__((address_space(1))) unsigned*)g,
                                   (__attribute__((address_space(3))) unsigned*)l, 16, 0, 0);
}

// counted-vmcnt barrier pair (T3/T4 minimum form, m201 pattern):
// BAR1(N): wait own tile's loads (leave newer tiles' N in flight), then barrier.
// BAR2: drain ds_reads (protect buffer overwrite), then barrier.
// NOTE: N must be a LITERAL (stringized into asm) -- dispatch constexpr values
// via if constexpr at the call site.
#define BAR1_N(N) do { asm volatile("s_waitcnt vmcnt(" #N ")" ::: "memory"); \
                       __builtin_amdgcn_s_barrier(); } while (0)
#define BAR2() do { asm volatile("s_waitcnt lgkmcnt(0)" ::: "memory"); \
                    __builtin_amdgcn_s_barrier(); } while (0)

// element-index swizzle for 64-col bf16 LDS tiles (16B chunk XOR row&7)
#define ASW(row, chunk) (((row) << 6) + ((((chunk) ^ ((row)&7))) << 3))

// ---------- fused weight cast fp32 -> bf16 (7 segments, contiguous dst arena) ----------
__global__ void k_castall(const float* __restrict__ s0, const float* __restrict__ s1,
                          const float* __restrict__ s2, const float* __restrict__ s3,
                          const float* __restrict__ s4, const float* __restrict__ s5,
                          const float* __restrict__ s6, bf16* __restrict__ dst) {
  const size_t DM2 = (size_t)DM * DM;
  size_t u = ((size_t)blockIdx.x * 256 + threadIdx.x) * 4;
  if (u >= 17 * DM2) return;
  const float* src;
  size_t loc;
  if (u < 3 * DM2) { src = s0; loc = u; }
  else if (u < 4 * DM2) { src = s1; loc = u - 3 * DM2; }
  else if (u < 5 * DM2) { src = s2; loc = u - 4 * DM2; }
  else if (u < 7 * DM2) { src = s3; loc = u - 5 * DM2; }
  else if (u < 8 * DM2) { src = s4; loc = u - 7 * DM2; }
  else if (u < 14 * DM2) { src = s5; loc = u - 8 * DM2; }
  else { src = s6; loc = u - 14 * DM2; }
  float4 v = *(const float4*)&src[loc];
  bf16* d = dst + u;
  d[0] = __float2bfloat16(v.x);
  d[1] = __float2bfloat16(v.y);
  d[2] = __float2bfloat16(v.z);
  d[3] = __float2bfloat16(v.w);
}

// ---------- RMSNorm: one block (256 thr) per row of 768; bf16 out ----------
__device__ __forceinline__ void rms_body(const float* __restrict__ in,
                                         const float* __restrict__ scale, int row, int t,
                                         bf16* __restrict__ out) {
  const float* r = in + (size_t)row * DM;
  float x0 = r[t], x1 = r[t + 256], x2 = r[t + 512];
  float ss = x0 * x0 + x1 * x1 + x2 * x2;
  ss = waveSum(ss);
  __shared__ float red[4];
  int w = t >> 6, ln = t & 63;
  if (ln == 0) red[w] = ss;
  __syncthreads();
  float tot = red[0] + red[1] + red[2] + red[3];
  float g = rsqrtf(tot / (float)DM + 1e-6f);
  bf16* o = out + (size_t)row * DM;
  o[t] = __float2bfloat16(x0 * g * scale[t]);
  o[t + 256] = __float2bfloat16(x1 * g * scale[t + 256]);
  o[t + 512] = __float2bfloat16(x2 * g * scale[t + 512]);
}

__global__ __launch_bounds__(256) void k_rmsnorm(const float* __restrict__ in,
                                                 const float* __restrict__ scale,
                                                 bf16* __restrict__ out) {
  rms_body(in, scale, blockIdx.x, threadIdx.x, out);
}

// two independent rmsnorms in one dispatch (x and x_cross prologue)
__global__ __launch_bounds__(256) void k_rmsnorm2(const float* __restrict__ in0,
                                                  const float* __restrict__ sc0,
                                                  bf16* __restrict__ out0,
                                                  const float* __restrict__ in1,
                                                  const float* __restrict__ sc1,
                                                  bf16* __restrict__ out1) {
  int row = blockIdx.x;
  if (row < M_TOK) rms_body(in0, sc0, row, threadIdx.x, out0);
  else rms_body(in1, sc1, row - M_TOK, threadIdx.x, out1);
}

// ---------- MFMA GEMM, BK=64 double-buffered K-loop, counted-vmcnt barriers ----------
// 32 MFMA per wave per barrier pair (2x the BK=32 form): half the barriers.
// 64-col LDS rows with ASW swizzle. (R8 proven config.)
template <int NT, int OBF>
__global__ __launch_bounds__(256) void k_gemm(const bf16* __restrict__ A,
                                              const bf16* __restrict__ W,
                                              float* __restrict__ C,
                                              bf16* __restrict__ Cb,
                                              const float* __restrict__ res,
                                              int M, int N, int K) {
  __shared__ __align__(16) bf16 As[2 * 128 * 64];
  __shared__ __align__(16) bf16 Bs[2 * NT * 64];
  const int t = threadIdx.x;
  const int w = t >> 6, lane = t & 63;
  const int m0 = blockIdx.y * 128, n0 = blockIdx.x * NT;
  const int quad = lane >> 4, l16 = lane & 15;
  constexpr int MI = (NT == 128) ? 4 : 2;
  const int wrow = (NT == 128) ? (w >> 1) * 64 : w * 32;
  const int wcol = (NT == 128) ? (w & 1) * 64 : 0;

  ffrag acc[MI][4];
#pragma unroll
  for (int i = 0; i < MI; i++)
#pragma unroll
    for (int j = 0; j < 4; j++) acc[i][j] = (ffrag){0.f, 0.f, 0.f, 0.f};

  // hoisted staging pointers (advance 64 elems per staged K-tile)
  const bf16 *pA[4], *pB[4];
  int lA[4], lB[4];
#pragma unroll
  for (int it = 0; it < 4; it++) {
    int lc = (w * 4 + it) * 64 + lane;
    int r = lc >> 3, c = lc & 7, kc = c ^ (r & 7);
    pA[it] = A + (size_t)(m0 + r) * K + kc * 8;
    lA[it] = lc * 8;
  }
  if (NT == 128) {
#pragma unroll
    for (int it = 0; it < 4; it++) {
      int lc = (w * 4 + it) * 64 + lane;
      int r = lc >> 3, c = lc & 7, kc = c ^ (r & 7);
      pB[it] = W + (size_t)(n0 + r) * K + kc * 8;
      lB[it] = lc * 8;
    }
  } else {
#pragma unroll
    for (int it = 0; it < 2; it++) {
      int lc = (w * 2 + it) * 64 + lane;
      int r = lc >> 3, c = lc & 7, kc = c ^ (r & 7);
      pB[it] = W + (size_t)(n0 + r) * K + kc * 8;
      lB[it] = lc * 8;
    }
  }
  auto stage = [&](int sel) {
#pragma unroll
    for (int it = 0; it < 4; it++) { gld16(&As[sel * 8192 + lA[it]], pA[it]); pA[it] += 64; }
    if (NT == 128) {
#pragma unroll
      for (int it = 0; it < 4; it++) { gld16(&Bs[sel * 8192 + lB[it]], pB[it]); pB[it] += 64; }
    } else {
#pragma unroll
      for (int it = 0; it < 2; it++) { gld16(&Bs[sel * 4096 + lB[it]], pB[it]); pB[it] += 64; }
    }
  };

  const int NK = K >> 6; // 12 or 36
  stage(0);
  for (int kt = 0; kt < NK; kt++) {
    int cur = kt & 1;
    if (kt + 1 < NK) {
      stage(cur ^ 1);
      if constexpr (NT == 128) { BAR1_N(8); } else { BAR1_N(6); }
    } else {
      BAR1_N(0);
    }
    const bf16* Ab = As + cur * 8192;
    const bf16* Bb = Bs + cur * (NT == 128 ? 8192 : 4096);
#pragma unroll
    for (int s = 0; s < 2; s++) {
      bfrag af[MI], bfv[4];
#pragma unroll
      for (int i = 0; i < MI; i++)
        af[i] = *(const bfrag*)&Ab[ASW(wrow + i * 16 + l16, s * 4 + quad)];
#pragma unroll
      for (int j = 0; j < 4; j++)
        bfv[j] = *(const bfrag*)&Bb[ASW(wcol + j * 16 + l16, s * 4 + quad)];
#pragma unroll
      for (int i = 0; i < MI; i++)
#pragma unroll
        for (int j = 0; j < 4; j++)
          acc[i][j] = __builtin_amdgcn_mfma_f32_16x16x32_bf16(af[i], bfv[j], acc[i][j], 0, 0, 0);
    }
    BAR2();
  }
#pragma unroll
  for (int i = 0; i < MI; i++) {
    int mrow = m0 + wrow + i * 16 + quad * 4;
#pragma unroll
    for (int j = 0; j < 4; j++) {
      int ncol = n0 + wcol + j * 16 + l16;
#pragma unroll
      for (int r = 0; r < 4; r++) {
        float v = acc[i][j][r];
        size_t idx = (size_t)(mrow + r) * N + ncol;
        if (OBF) {
          Cb[idx] = __float2bfloat16(v);
        } else {
          if (res) v += res[idx];
          C[idx] = v;
        }
      }
    }
  }
}

// ---------- fused ff_up + SwiGLU, BK=32 (R5 proven config) ----------
__global__ __launch_bounds__(256) void k_ffup(const bf16* __restrict__ A,
                                              const bf16* __restrict__ Wup,
                                              bf16* __restrict__ Out) {
  __shared__ __align__(16) bf16 As[2 * 128 * 32];
  __shared__ __align__(16) bf16 Ba[2 * 64 * 32];
  __shared__ __align__(16) bf16 Bg[2 * 64 * 32];
  const int t = threadIdx.x, w = t >> 6, lane = t & 63;
  const int m0 = blockIdx.y * 128, n0 = blockIdx.x * 64;
  const int quad = lane >> 4, l16 = lane & 15;

  ffrag aa[2][4], ag[2][4];
#pragma unroll
  for (int i = 0; i < 2; i++)
#pragma unroll
    for (int j = 0; j < 4; j++) {
      aa[i][j] = (ffrag){0.f, 0.f, 0.f, 0.f};
      ag[i][j] = (ffrag){0.f, 0.f, 0.f, 0.f};
    }

  const bf16 *pA0, *pA1, *pBa, *pBg;
  int lA0, lA1, lBc;
  {
    int lc0 = (w * 2 + 0) * 64 + lane;
    int r0 = lc0 >> 2, kc0 = (lc0 & 3) ^ ((r0 >> 1) & 3);
    int lc1 = (w * 2 + 1) * 64 + lane;
    int r1 = lc1 >> 2, kc1 = (lc1 & 3) ^ ((r1 >> 1) & 3);
    pA0 = A + (size_t)(m0 + r0) * DM + kc0 * 8; lA0 = lc0 * 8;
    pA1 = A + (size_t)(m0 + r1) * DM + kc1 * 8; lA1 = lc1 * 8;
    int lc = w * 64 + lane;
    int r = lc >> 2, kc = (lc & 3) ^ ((r >> 1) & 3);
    pBa = Wup + (size_t)(n0 + r) * DM + kc * 8;
    pBg = Wup + (size_t)(DFF + n0 + r) * DM + kc * 8;
    lBc = lc * 8;
  }
  auto stage = [&](int sel) {
    gld16(&As[sel * 4096 + lA0], pA0); pA0 += 32;
    gld16(&As[sel * 4096 + lA1], pA1); pA1 += 32;
    gld16(&Ba[sel * 2048 + lBc], pBa); pBa += 32;
    gld16(&Bg[sel * 2048 + lBc], pBg); pBg += 32;
  };

  const int NK = DM / 32;
  stage(0);
  for (int kt = 0; kt < NK; kt++) {
    int cur = kt & 1;
    if (kt + 1 < NK) {
      stage(cur ^ 1);
      BAR1_N(4);
    } else {
      BAR1_N(0);
    }
    const bf16* Ab = As + cur * 4096;
    const bf16* Bab = Ba + cur * 2048;
    const bf16* Bgb = Bg + cur * 2048;
    bfrag af[2], ba[4], bg[4];
#pragma unroll
    for (int i = 0; i < 2; i++) {
      int r = w * 32 + i * 16 + l16;
      af[i] = *(const bfrag*)&Ab[r * 32 + (quad ^ ((r >> 1) & 3)) * 8];
    }
#pragma unroll
    for (int j = 0; j < 4; j++) {
      int r = j * 16 + l16;
      int sw = (quad ^ ((r >> 1) & 3)) * 8;
      ba[j] = *(const bfrag*)&Bab[r * 32 + sw];
      bg[j] = *(const bfrag*)&Bgb[r * 32 + sw];
    }
#pragma unroll
    for (int i = 0; i < 2; i++)
#pragma unroll
      for (int j = 0; j < 4; j++) {
        aa[i][j] = __builtin_amdgcn_mfma_f32_16x16x32_bf16(af[i], ba[j], aa[i][j], 0, 0, 0);
        ag[i][j] = __builtin_amdgcn_mfma_f32_16x16x32_bf16(af[i], bg[j], ag[i][j], 0, 0, 0);
      }
    BAR2();
  }
#pragma unroll
  for (int i = 0; i < 2; i++) {
    int mrow = m0 + w * 32 + i * 16 + quad * 4;
#pragma unroll
    for (int j = 0; j < 4; j++) {
      int ncol = n0 + j * 16 + l16;
#pragma unroll
      for (int r = 0; r < 4; r++) {
        float a = aa[i][j][r], g = ag[i][j][r];
        float v = a * g / (1.f + __expf(-g));
        Out[(size_t)(mrow + r) * DFF + ncol] = __float2bfloat16(v);
      }
    }
  }
}

// ---------- cos-scale + RoPE, vectorized: one wave = 8 tokens, lane = (tok,8-chunk) ----------
__device__ __forceinline__ void rope8(const bf16* __restrict__ inp, const float* __restrict__ pos3,
                                      float s, float fr0, int k, int lane,
                                      bf16* __restrict__ outp) {
  bfrag v = *(const bfrag*)inp;
  float x[8];
#pragma unroll
  for (int i = 0; i < 8; i++) x[i] = __bfloat162float(__builtin_bit_cast(bf16, (short)v[i]));
  float ss = 0.f;
#pragma unroll
  for (int i = 0; i < 8; i++) ss += x[i] * x[i];
  ss += __shfl_xor(ss, 1, 64);
  ss += __shfl_xor(ss, 2, 64);
  ss += __shfl_xor(ss, 4, 64);
  float g = s * rsqrtf(ss + 1e-6f);
#pragma unroll
  for (int i = 0; i < 8; i++) x[i] *= g;
  int pk = k < 3 ? k + 3 : (k < 6 ? k - 3 : k);
  int psrc = (lane & 56) | pk;
  float other[8];
#pragma unroll
  for (int i = 0; i < 8; i++) other[i] = __shfl(x[i], psrc, 64);
  bfrag o;
  if (k < 6) {
    int c = k < 3 ? k : k - 3;
    float p = pos3[c];
    float fr = fr0;
    float sgn = k < 3 ? -1.f : 1.f;
#pragma unroll
    for (int i = 0; i < 8; i++) {
      float th = p * fr;
      fr *= 1.333521432163324f; // 10^(1/8)
      float st = __sinf(th), ct = __cosf(th);
      o[i] = __builtin_bit_cast(short, __float2bfloat16(x[i] * ct + sgn * other[i] * st));
    }
  } else {
#pragma unroll
    for (int i = 0; i < 8; i++) o[i] = __builtin_bit_cast(short, __float2bfloat16(x[i]));
  }
  *(bfrag*)outp = o;
}

__global__ __launch_bounds__(256) void k_ropeqk(const bf16* __restrict__ inQ, int strQ, int offQ,
                                                const bf16* __restrict__ inK, int strK, int offK,
                                                const float* __restrict__ posQ,
                                                const float* __restrict__ posK,
                                                const float* __restrict__ scale,
                                                bf16* __restrict__ outQ, bf16* __restrict__ outK) {
  int wid = blockIdx.x * 4 + (threadIdx.x >> 6);
  int lane = threadIdx.x & 63;
  int k = lane & 7;
  int item = wid * 8 + (lane >> 3); // (b*NH + h)*L + l ; bh uniform per wave (8|L)
  int l = item % L;
  int bh = item / L;
  int h = bh % NH;
  int b = bh / NH;
  float s = sqrtf(scale[h]);
  float fr0 = __expf(1.14472988584940017f + (float)h * 0.023985261385354646f);
  size_t tokrow = (size_t)(b * L + l);
  rope8(inQ + tokrow * strQ + offQ + h * DH + k * 8, &posQ[tokrow * 3], s, fr0, k, lane,
        outQ + (size_t)item * DH + k * 8);
  rope8(inK + tokrow * strK + offK + h * DH + k * 8, &posK[tokrow * 3], s, fr0, k, lane,
        outK + (size_t)item * DH + k * 8);
}

// ---------- V transpose: (b,l,h,d)-strided slice -> Vt (bh, DH, L) ----------
// Keys are stored PERMUTED within each 16-token group: slot p holds token
// swap23(p) (bits 2<->3), matching the native key order of QK^T output frags.
__global__ __launch_bounds__(256) void k_vtrans(const bf16* __restrict__ in, int stride, int off,
                                                bf16* __restrict__ Vt) {
  __shared__ __align__(16) bf16 St[64 * 64];
  int lt = blockIdx.x & 31, bh = blockIdx.x >> 5;
  int h = bh % NH, b = bh / NH;
  int t = threadIdx.x;
#pragma unroll
  for (int pass = 0; pass < 2; pass++) {
    int cid = t + pass * 256;
    int r = cid >> 3, c = cid & 7; // token r, d-chunk c
    *(float4*)&St[ASW(r, c)] =
        *(const float4*)&in[(size_t)(b * L + lt * 64 + r) * stride + off + h * DH + c * 8];
  }
  __syncthreads();
  const short* Ss = (const short*)St;
#pragma unroll
  for (int pass = 0; pass < 2; pass++) {
    int cid = t + pass * 256;
    int d = cid >> 3, oc = cid & 7; // out row d, slot-chunk oc
    bfrag tmp;
#pragma unroll
    for (int i = 0; i < 8; i++) {
      int p = oc * 8 + i;
      int tok = (p & ~12) | ((p & 4) << 1) | ((p & 8) >> 1); // swap bits 2,3
      tmp[i] = Ss[(tok << 6) + ((((d >> 3) ^ (tok & 7))) << 3) + (d & 7)];
    }
    *(bfrag*)&Vt[((size_t)bh * DH + d) * L + lt * 64 + oc * 8] = tmp;
  }
}

// ---------- MFMA flash attention, 32x32x16, fixed-bound softmax ----------
// P fully in-register (swap23-permuted V); 3-buffer KV rotation with a single
// counted barrier per KV tile (R9 verified). NEW: TWO 64-query tiles per
// block -- Q frags and accumulators double, but LDS / staging / barrier
// count are unchanged, so per-barrier MFMA doubles (8->16 per wave) and
// K/V L2 traffic halves (grid 768 -> 384 blocks).
__global__ __launch_bounds__(256) void k_attn_mfma(const bf16* __restrict__ Q,
                                                   const bf16* __restrict__ K,
                                                   const bf16* __restrict__ Vt,
                                                   const float* __restrict__ scale,
                                                   bf16* __restrict__ O) {
  __shared__ __align__(16) char smem[49152 + 512];
  bf16* Ks = (bf16*)smem;               // 3 x 8KB [key][d]
  bf16* Vs = (bf16*)(smem + 24576);     // 3 x 8KB [d][key-permuted]
  float* Oex = (float*)smem;            // 16KB overlay (after final barrier)
  float* Lred = (float*)(smem + 49152); // 2*64
  int qt = blockIdx.x & 15, bh = blockIdx.x >> 4; // 128 queries per block
  int h = bh % NH, b = bh / NH;
  float smax = scale[h];
  float nsl2 = -smax * 1.442695040888963f; // -smax * log2(e)
  int t = threadIdx.x, w = t >> 6, lane = t & 63;
  int hh = lane >> 5, l32 = lane & 31;
  int qsub = w >> 1, ksub = w & 1;

  const bf16* kbase = K + (size_t)(bh * L) * DH;
  const bf16* vbase = Vt + (size_t)bh * DH * L;

  // Q B-frags for both 64-query sub-tiles (A: qt*128, B: qt*128+64)
  const bf16* qrowA = Q + ((size_t)(bh * L) + qt * 128 + qsub * 32 + l32) * DH;
  const bf16* qrowB = qrowA + (size_t)64 * DH;
  bfrag qfA[4], qfB[4];
#pragma unroll
  for (int c = 0; c < 4; c++) {
    qfA[c] = *(const bfrag*)&qrowA[c * 16 + hh * 8];
    qfB[c] = *(const bfrag*)&qrowB[c * 16 + hh * 8];
  }

  facc16 o0A, o1A, o0B, o1B;
#pragma unroll
  for (int i = 0; i < 16; i++) { o0A[i] = 0.f; o1A[i] = 0.f; o0B[i] = 0.f; o1B[i] = 0.f; }
  float lA = 0.f, lB = 0.f;

  // hoisted staging pointers: kg += 64*DH, vg += 64 per tile
  const bf16 *kg0, *kg1, *vg0, *vg1;
  int lk0, lk1;
  {
    int r0 = w * 8 + (lane >> 3);
    int kc0 = (lane & 7) ^ (r0 & 7);
    int r1 = r0 + 32;
    int kc1 = (lane & 7) ^ (r1 & 7);
    kg0 = kbase + (size_t)r0 * DH + kc0 * 8;
    kg1 = kbase + (size_t)r1 * DH + kc1 * 8;
    vg0 = vbase + (size_t)r0 * L + kc0 * 8;
    vg1 = vbase + (size_t)r1 * L + kc1 * 8;
    lk0 = (w * 8) * 64 + lane * 8;
    lk1 = (w * 8 + 32) * 64 + lane * 8;
  }
  auto stageKV = [&](int sel) {
    gld16(&Ks[sel * 4096 + lk0], kg0); kg0 += 64 * DH;
    gld16(&Ks[sel * 4096 + lk1], kg1); kg1 += 64 * DH;
    gld16(&Vs[sel * 4096 + lk0], vg0); vg0 += 64;
    gld16(&Vs[sel * 4096 + lk1], vg1); vg1 += 64;
  };

  stageKV(0);
  stageKV(1);
  int cur = 0;
  for (int kt = 0; kt < 32; kt++) {
    if (kt < 31) { BAR1_N(4); } else { BAR1_N(0); } // tile kt ready
    if (kt + 2 < 32) {
      int nb = cur + 2; if (nb >= 3) nb -= 3;
      stageKV(nb); // writes buf (kt-1)%3: its readers finished pre-barrier
    }
    const bf16* Kb = Ks + cur * 4096;
    const bf16* Vb = Vs + cur * 4096;
    bfrag vf0 = *(const bfrag*)&Vb[ASW(l32, ksub * 4 + hh)];
    bfrag vf1 = *(const bfrag*)&Vb[ASW(l32, ksub * 4 + 2 + hh)];
    bfrag vf2 = *(const bfrag*)&Vb[ASW(32 + l32, ksub * 4 + hh)];
    bfrag vf3 = *(const bfrag*)&Vb[ASW(32 + l32, ksub * 4 + 2 + hh)];
#pragma unroll
    for (int sub = 0; sub < 2; sub++) {
      const bfrag* qf = sub ? qfB : qfA;
      // ---- S^T = K·Q^T (m=key 32 of ksub, n=q 32 of qsub, k=d 64) ----
      facc16 s;
#pragma unroll
      for (int i = 0; i < 16; i++) s[i] = 0.f;
#pragma unroll
      for (int c = 0; c < 4; c++) {
        bfrag kf = *(const bfrag*)&Kb[ASW(ksub * 32 + l32, c * 2 + hh)];
        s = __builtin_amdgcn_mfma_f32_32x32x16_bf16(kf, qf[c], s, 0, 0, 0);
      }
      // ---- p = exp2(s*log2e - smax*log2e); 2 partial sums (break add chain) ----
      float pv[16];
      float lp0 = 0.f, lp1 = 0.f;
#pragma unroll
      for (int reg = 0; reg < 16; reg += 2) {
        float p0 = __builtin_amdgcn_exp2f(__builtin_fmaf(s[reg], 1.442695040888963f, nsl2));
        float p1 = __builtin_amdgcn_exp2f(__builtin_fmaf(s[reg + 1], 1.442695040888963f, nsl2));
        lp0 += p0; lp1 += p1;
        pv[reg] = p0; pv[reg + 1] = p1;
      }
      if (sub) lB += lp0 + lp1; else lA += lp0 + lp1;
      // ---- pack P directly into A-frags (native key order = swap23 slots) ----
      bfrag pf0, pf1;
#pragma unroll
      for (int j = 0; j < 8; j++) {
        pf0[j] = __builtin_bit_cast(short, __float2bfloat16(pv[j]));
        pf1[j] = __builtin_bit_cast(short, __float2bfloat16(pv[8 + j]));
      }
      // ---- O partial += P(own keys) · V (V stored key-permuted to match) ----
      facc16& e0 = sub ? o0B : o0A;
      facc16& e1 = sub ? o1B : o1A;
      e0 = __builtin_amdgcn_mfma_f32_32x32x16_bf16(pf0, vf0, e0, 0, 0, 0);
      e0 = __builtin_amdgcn_mfma_f32_32x32x16_bf16(pf1, vf1, e0, 0, 0, 0);
      e1 = __builtin_amdgcn_mfma_f32_32x32x16_bf16(pf0, vf2, e1, 0, 0, 0);
      e1 = __builtin_amdgcn_mfma_f32_32x32x16_bf16(pf1, vf3, e1, 0, 0, 0);
    }
    cur = (cur == 2) ? 0 : cur + 1;
  }
  // ---- epilogue per sub-tile: merge key-halves via Oex overlay ----
#pragma unroll
  for (int sub = 0; sub < 2; sub++) {
    facc16& e0 = sub ? o0B : o0A;
    facc16& e1 = sub ? o1B : o1A;
    float l_run = sub ? lB : lA;
    l_run += __shfl_xor(l_run, 32, 64);
    __syncthreads(); // PV reads (sub 0) / prior Oex reads (sub 1) complete
    {
      int gd = (ksub ^ 1) * 32 + l32;
#pragma unroll
      for (int reg = 0; reg < 16; reg++) {
        int row = (reg & 3) + 8 * (reg >> 2) + 4 * hh;
        float gv = ksub ? e0[reg] : e1[reg];
        Oex[(size_t)(qsub * 32 + row) * 64 + gd] = gv;
      }
    }
    if (lane < 32) Lred[ksub * 64 + qsub * 32 + lane] = l_run;
    __syncthreads();
    {
      int d = ksub * 32 + l32;
#pragma unroll
      for (int reg = 0; reg < 16; reg++) {
        int row = (reg & 3) + 8 * (reg >> 2) + 4 * hh;
        int qg2 = qsub * 32 + row;
        float ltot = Lred[qg2] + Lred[64 + qg2];
        float keep = ksub ? e1[reg] : e0[reg];
        float v = (keep + Oex[(size_t)qg2 * 64 + d]) / ltot;
        O[(((size_t)(b * L) + qt * 128 + sub * 64 + qg2) * NH + h) * DH + d] =
            __float2bfloat16(v);
      }
    }
  }
}

extern "C" void kernel_launch(void* const* d_in, const int* in_sizes, int n_in,
                              void* d_out, int out_size, void* d_ws, size_t ws_size,
                              hipStream_t stream) {
  const float* x = (const float*)d_in[0];
  const float* pos = (const float*)d_in[1];
  const float* x_cross = (const float*)d_in[2];
  const float* pos_cross = (const float*)d_in[3];
  const float* sa_norm_scale = (const float*)d_in[4];
  const float* sa_wqkv = (const float*)d_in[5];
  const float* sa_scale = (const float*)d_in[6];
  const float* sa_wout = (const float*)d_in[7];
  const float* ca_norm_scale = (const float*)d_in[8];
  const float* ca_norm_cross_scale = (const float*)d_in[9];
  const float* ca_wq = (const float*)d_in[10];
  const float* ca_wkv = (const float*)d_in[11];
  const float* ca_scale = (const float*)d_in[12];
  const float* ca_wout = (const float*)d_in[13];
  const float* ff_norm_scale = (const float*)d_in[14];
  const float* ff_wup = (const float*)d_in[15];
  const float* ff_wdown = (const float*)d_in[16];
  float* out = (float*)d_out;

  float* ws = (float*)d_ws;
  const size_t S = (size_t)M_TOK * DM; // 3,145,728
  float* xbuf = ws; // S f32: running residual
  bf16* b16 = (bf16*)(ws + S);
  bf16* qkvb = b16;        // 3S: qkv (self) / caq + cakv (cross) / ffact (FF)
  bf16* qb = b16 + 3 * S;  // (BH, L, DH)
  bf16* kb = b16 + 4 * S;  // (BH, L, DH)
  bf16* vtb = b16 + 5 * S; // (BH, DH, L) key-permuted
  bf16* hb = b16 + 6 * S;
  bf16* hcb = b16 + 7 * S;
  bf16* obb = b16 + 8 * S; // attn out (B,L,NH,DH)
  bf16* wqkvb = b16 + 9 * S; // weight arena: 17*DM*DM contiguous, castall order
  bf16* woutb = wqkvb + (size_t)3 * DM * DM;
  bf16* wqb = woutb + (size_t)DM * DM;
  bf16* wkvb = wqb + (size_t)DM * DM;
  bf16* wout2b = wkvb + (size_t)2 * DM * DM;
  bf16* wupb = wout2b + (size_t)DM * DM;
  bf16* wdownb = wupb + (size_t)2 * DFF * DM;
  bf16* ffb = qkvb;

  const int ropeGrid = B * NH * L / 32; // 8 tokens/wave, 4 waves/block
  const int attnGrid = B * NH * (L / 128); // 384 (2 q-tiles per block)
  const int vtGrid = B * NH * (L / 64);   // 768
  const size_t DM2 = (size_t)DM * DM;
  const int castGrid = (int)((17 * DM2 / 4 + 255) / 256);

  k_castall<<<castGrid, 256, 0, stream>>>(sa_wqkv, sa_wout, ca_wq, ca_wkv, ca_wout, ff_wup,
                                          ff_wdown, wqkvb);

  // ---- merged prologue norms: self (x) + cross (x_cross) ----
  k_rmsnorm2<<<2 * M_TOK, 256, 0, stream>>>(x, sa_norm_scale, hb, x_cross, ca_norm_cross_scale,
                                            hcb);

  // ---- self attention ----
  k_gemm<128, 1><<<dim3(3 * DM / 128, M_TOK / 128), 256, 0, stream>>>(
      hb, wqkvb, nullptr, qkvb, nullptr, M_TOK, 3 * DM, DM);
  k_ropeqk<<<ropeGrid, 256, 0, stream>>>(qkvb, 3 * DM, 0, qkvb, 3 * DM, DM, pos, pos, sa_scale,
                                         qb, kb);
  k_vtrans<<<vtGrid, 256, 0, stream>>>(qkvb, 3 * DM, 2 * DM, vtb);
  k_attn_mfma<<<attnGrid, 256, 0, stream>>>(qb, kb, vtb, sa_scale, obb);
  k_gemm<64, 0><<<dim3(DM / 64, M_TOK / 128), 256, 0, stream>>>(
      obb, woutb, xbuf, nullptr, x, M_TOK, DM, DM); // xbuf = attn@wout + x

  // ---- cross attention ----
  k_rmsnorm<<<M_TOK, 256, 0, stream>>>(xbuf, ca_norm_scale, hb);
  k_gemm<64, 1><<<dim3(DM / 64, M_TOK / 128), 256, 0, stream>>>(
      hb, wqb, nullptr, qkvb, nullptr, M_TOK, DM, DM);
  k_gemm<128, 1><<<dim3(2 * DM / 128, M_TOK / 128), 256, 0, stream>>>(
      hcb, wkvb, nullptr, qkvb + S, nullptr, M_TOK, 2 * DM, DM);
  k_ropeqk<<<ropeGrid, 256, 0, stream>>>(qkvb, DM, 0, qkvb + S, 2 * DM, 0, pos, pos_cross,
                                         ca_scale, qb, kb);
  k_vtrans<<<vtGrid, 256, 0, stream>>>(qkvb + S, 2 * DM, DM, vtb);
  k_attn_mfma<<<attnGrid, 256, 0, stream>>>(qb, kb, vtb, ca_scale, obb);
  k_gemm<64, 0><<<dim3(DM / 64, M_TOK / 128), 256, 0, stream>>>(
      obb, wout2b, xbuf, nullptr, xbuf, M_TOK, DM, DM);

  // ---- feed-forward (fused up+SwiGLU, then down) ----
  k_rmsnorm<<<M_TOK, 256, 0, stream>>>(xbuf, ff_norm_scale, hb);
  k_ffup<<<dim3(DFF / 64, M_TOK / 128), 256, 0, stream>>>(hb, wupb, ffb);
  k_gemm<64, 0><<<dim3(DM / 64, M_TOK / 128), 256, 0, stream>>>(
      ffb, wdownb, out, nullptr, xbuf, M_TOK, DM, DFF);
}

// Round 11
// 426.399 us; speedup vs baseline: 1.0515x; 1.0515x over previous
//
#include <hip/hip_runtime.h>
#include <hip/hip_bf16.h>
#include <math.h>

typedef __hip_bfloat16 bf16;

#define B 2
#define L 2048
#define DM 768
#define NH 12
#define DH 64
#define DFF 2304
#define M_TOK (B * L) // 4096

typedef __attribute__((ext_vector_type(8))) short bfrag;
typedef __attribute__((ext_vector_type(4))) float ffrag;
typedef __attribute__((ext_vector_type(16))) float facc16;

__device__ __forceinline__ float waveSum(float v) {
#pragma unroll
  for (int o = 32; o > 0; o >>= 1) v += __shfl_down(v, o, 64);
  return v;
}

__device__ __forceinline__ void gld16(void* l, const void* g) {
  __builtin_amdgcn_global_load_lds((const __attribute__((address_space(1))) unsigned*)g,
                                   (__attribute__((address_space(3))) unsigned*)l, 16, 0, 0);
}

// counted-vmcnt barrier pair (T3/T4 minimum form, m201 pattern):
// BAR1(N): wait own tile's loads (leave newer tiles' N in flight), then barrier.
// BAR2: drain ds_reads (protect buffer overwrite), then barrier.
// NOTE: N must be a LITERAL (stringized into asm) -- dispatch constexpr values
// via if constexpr at the call site.
#define BAR1_N(N) do { asm volatile("s_waitcnt vmcnt(" #N ")" ::: "memory"); \
                       __builtin_amdgcn_s_barrier(); } while (0)
#define BAR2() do { asm volatile("s_waitcnt lgkmcnt(0)" ::: "memory"); \
                    __builtin_amdgcn_s_barrier(); } while (0)

// element-index swizzle for 64-col bf16 LDS tiles (16B chunk XOR row&7)
#define ASW(row, chunk) (((row) << 6) + ((((chunk) ^ ((row)&7))) << 3))

// ---------- fused weight cast fp32 -> bf16 (7 segments, contiguous dst arena) ----------
__global__ void k_castall(const float* __restrict__ s0, const float* __restrict__ s1,
                          const float* __restrict__ s2, const float* __restrict__ s3,
                          const float* __restrict__ s4, const float* __restrict__ s5,
                          const float* __restrict__ s6, bf16* __restrict__ dst) {
  const size_t DM2 = (size_t)DM * DM;
  size_t u = ((size_t)blockIdx.x * 256 + threadIdx.x) * 4;
  if (u >= 17 * DM2) return;
  const float* src;
  size_t loc;
  if (u < 3 * DM2) { src = s0; loc = u; }
  else if (u < 4 * DM2) { src = s1; loc = u - 3 * DM2; }
  else if (u < 5 * DM2) { src = s2; loc = u - 4 * DM2; }
  else if (u < 7 * DM2) { src = s3; loc = u - 5 * DM2; }
  else if (u < 8 * DM2) { src = s4; loc = u - 7 * DM2; }
  else if (u < 14 * DM2) { src = s5; loc = u - 8 * DM2; }
  else { src = s6; loc = u - 14 * DM2; }
  float4 v = *(const float4*)&src[loc];
  bf16* d = dst + u;
  d[0] = __float2bfloat16(v.x);
  d[1] = __float2bfloat16(v.y);
  d[2] = __float2bfloat16(v.z);
  d[3] = __float2bfloat16(v.w);
}

// ---------- RMSNorm: one block (256 thr) per row of 768; bf16 out ----------
__device__ __forceinline__ void rms_body(const float* __restrict__ in,
                                         const float* __restrict__ scale, int row, int t,
                                         bf16* __restrict__ out) {
  const float* r = in + (size_t)row * DM;
  float x0 = r[t], x1 = r[t + 256], x2 = r[t + 512];
  float ss = x0 * x0 + x1 * x1 + x2 * x2;
  ss = waveSum(ss);
  __shared__ float red[4];
  int w = t >> 6, ln = t & 63;
  if (ln == 0) red[w] = ss;
  __syncthreads();
  float tot = red[0] + red[1] + red[2] + red[3];
  float g = rsqrtf(tot / (float)DM + 1e-6f);
  bf16* o = out + (size_t)row * DM;
  o[t] = __float2bfloat16(x0 * g * scale[t]);
  o[t + 256] = __float2bfloat16(x1 * g * scale[t + 256]);
  o[t + 512] = __float2bfloat16(x2 * g * scale[t + 512]);
}

__global__ __launch_bounds__(256) void k_rmsnorm(const float* __restrict__ in,
                                                 const float* __restrict__ scale,
                                                 bf16* __restrict__ out) {
  rms_body(in, scale, blockIdx.x, threadIdx.x, out);
}

// two independent rmsnorms in one dispatch (x and x_cross prologue)
__global__ __launch_bounds__(256) void k_rmsnorm2(const float* __restrict__ in0,
                                                  const float* __restrict__ sc0,
                                                  bf16* __restrict__ out0,
                                                  const float* __restrict__ in1,
                                                  const float* __restrict__ sc1,
                                                  bf16* __restrict__ out1) {
  int row = blockIdx.x;
  if (row < M_TOK) rms_body(in0, sc0, row, threadIdx.x, out0);
  else rms_body(in1, sc1, row - M_TOK, threadIdx.x, out1);
}

// ---------- MFMA GEMM, BK=64 double-buffered K-loop, counted-vmcnt barriers ----------
// 32 MFMA per wave per barrier pair; 64-col LDS rows w/ ASW swizzle (R8 proven).
// NEW: XCD-chunked block remap (T1) -- each of 8 XCDs owns a contiguous
// m-range so every A-panel is resident in exactly ONE per-XCD L2.
// Bijective: all grids have nwg%8==0 and gridDim.y%8==0.
template <int NT, int OBF>
__global__ __launch_bounds__(256) void k_gemm(const bf16* __restrict__ A,
                                              const bf16* __restrict__ W,
                                              float* __restrict__ C,
                                              bf16* __restrict__ Cb,
                                              const float* __restrict__ res,
                                              int M, int N, int K) {
  __shared__ __align__(16) bf16 As[2 * 128 * 64];
  __shared__ __align__(16) bf16 Bs[2 * NT * 64];
  const int t = threadIdx.x;
  const int w = t >> 6, lane = t & 63;
  int orig = blockIdx.y * gridDim.x + blockIdx.x;
  int xcd = orig & 7, idx = orig >> 3;
  int mchunk = gridDim.y >> 3; // 4 (gridDim.y == 32 at every call site)
  int my = xcd * mchunk + idx / gridDim.x;
  int nx = idx % gridDim.x;
  const int m0 = my * 128, n0 = nx * NT;
  const int quad = lane >> 4, l16 = lane & 15;
  constexpr int MI = (NT == 128) ? 4 : 2;
  const int wrow = (NT == 128) ? (w >> 1) * 64 : w * 32;
  const int wcol = (NT == 128) ? (w & 1) * 64 : 0;

  ffrag acc[MI][4];
#pragma unroll
  for (int i = 0; i < MI; i++)
#pragma unroll
    for (int j = 0; j < 4; j++) acc[i][j] = (ffrag){0.f, 0.f, 0.f, 0.f};

  // hoisted staging pointers (advance 64 elems per staged K-tile)
  const bf16 *pA[4], *pB[4];
  int lA[4], lB[4];
#pragma unroll
  for (int it = 0; it < 4; it++) {
    int lc = (w * 4 + it) * 64 + lane;
    int r = lc >> 3, c = lc & 7, kc = c ^ (r & 7);
    pA[it] = A + (size_t)(m0 + r) * K + kc * 8;
    lA[it] = lc * 8;
  }
  if (NT == 128) {
#pragma unroll
    for (int it = 0; it < 4; it++) {
      int lc = (w * 4 + it) * 64 + lane;
      int r = lc >> 3, c = lc & 7, kc = c ^ (r & 7);
      pB[it] = W + (size_t)(n0 + r) * K + kc * 8;
      lB[it] = lc * 8;
    }
  } else {
#pragma unroll
    for (int it = 0; it < 2; it++) {
      int lc = (w * 2 + it) * 64 + lane;
      int r = lc >> 3, c = lc & 7, kc = c ^ (r & 7);
      pB[it] = W + (size_t)(n0 + r) * K + kc * 8;
      lB[it] = lc * 8;
    }
  }
  auto stage = [&](int sel) {
#pragma unroll
    for (int it = 0; it < 4; it++) { gld16(&As[sel * 8192 + lA[it]], pA[it]); pA[it] += 64; }
    if (NT == 128) {
#pragma unroll
      for (int it = 0; it < 4; it++) { gld16(&Bs[sel * 8192 + lB[it]], pB[it]); pB[it] += 64; }
    } else {
#pragma unroll
      for (int it = 0; it < 2; it++) { gld16(&Bs[sel * 4096 + lB[it]], pB[it]); pB[it] += 64; }
    }
  };

  const int NK = K >> 6; // 12 or 36
  stage(0);
  for (int kt = 0; kt < NK; kt++) {
    int cur = kt & 1;
    if (kt + 1 < NK) {
      stage(cur ^ 1);
      if constexpr (NT == 128) { BAR1_N(8); } else { BAR1_N(6); }
    } else {
      BAR1_N(0);
    }
    const bf16* Ab = As + cur * 8192;
    const bf16* Bb = Bs + cur * (NT == 128 ? 8192 : 4096);
#pragma unroll
    for (int s = 0; s < 2; s++) {
      bfrag af[MI], bfv[4];
#pragma unroll
      for (int i = 0; i < MI; i++)
        af[i] = *(const bfrag*)&Ab[ASW(wrow + i * 16 + l16, s * 4 + quad)];
#pragma unroll
      for (int j = 0; j < 4; j++)
        bfv[j] = *(const bfrag*)&Bb[ASW(wcol + j * 16 + l16, s * 4 + quad)];
#pragma unroll
      for (int i = 0; i < MI; i++)
#pragma unroll
        for (int j = 0; j < 4; j++)
          acc[i][j] = __builtin_amdgcn_mfma_f32_16x16x32_bf16(af[i], bfv[j], acc[i][j], 0, 0, 0);
    }
    BAR2();
  }
#pragma unroll
  for (int i = 0; i < MI; i++) {
    int mrow = m0 + wrow + i * 16 + quad * 4;
#pragma unroll
    for (int j = 0; j < 4; j++) {
      int ncol = n0 + wcol + j * 16 + l16;
#pragma unroll
      for (int r = 0; r < 4; r++) {
        float v = acc[i][j][r];
        size_t idx2 = (size_t)(mrow + r) * N + ncol;
        if (OBF) {
          Cb[idx2] = __float2bfloat16(v);
        } else {
          if (res) v += res[idx2];
          C[idx2] = v;
        }
      }
    }
  }
}

// ---------- fused ff_up + SwiGLU, BK=32 (R5 proven config) + XCD remap ----------
__global__ __launch_bounds__(256) void k_ffup(const bf16* __restrict__ A,
                                              const bf16* __restrict__ Wup,
                                              bf16* __restrict__ Out) {
  __shared__ __align__(16) bf16 As[2 * 128 * 32];
  __shared__ __align__(16) bf16 Ba[2 * 64 * 32];
  __shared__ __align__(16) bf16 Bg[2 * 64 * 32];
  const int t = threadIdx.x, w = t >> 6, lane = t & 63;
  int orig = blockIdx.y * gridDim.x + blockIdx.x;
  int xcd = orig & 7, idx = orig >> 3;
  int mchunk = gridDim.y >> 3; // 4
  int my = xcd * mchunk + idx / gridDim.x;
  int nx = idx % gridDim.x;
  const int m0 = my * 128, n0 = nx * 64;
  const int quad = lane >> 4, l16 = lane & 15;

  ffrag aa[2][4], ag[2][4];
#pragma unroll
  for (int i = 0; i < 2; i++)
#pragma unroll
    for (int j = 0; j < 4; j++) {
      aa[i][j] = (ffrag){0.f, 0.f, 0.f, 0.f};
      ag[i][j] = (ffrag){0.f, 0.f, 0.f, 0.f};
    }

  const bf16 *pA0, *pA1, *pBa, *pBg;
  int lA0, lA1, lBc;
  {
    int lc0 = (w * 2 + 0) * 64 + lane;
    int r0 = lc0 >> 2, kc0 = (lc0 & 3) ^ ((r0 >> 1) & 3);
    int lc1 = (w * 2 + 1) * 64 + lane;
    int r1 = lc1 >> 2, kc1 = (lc1 & 3) ^ ((r1 >> 1) & 3);
    pA0 = A + (size_t)(m0 + r0) * DM + kc0 * 8; lA0 = lc0 * 8;
    pA1 = A + (size_t)(m0 + r1) * DM + kc1 * 8; lA1 = lc1 * 8;
    int lc = w * 64 + lane;
    int r = lc >> 2, kc = (lc & 3) ^ ((r >> 1) & 3);
    pBa = Wup + (size_t)(n0 + r) * DM + kc * 8;
    pBg = Wup + (size_t)(DFF + n0 + r) * DM + kc * 8;
    lBc = lc * 8;
  }
  auto stage = [&](int sel) {
    gld16(&As[sel * 4096 + lA0], pA0); pA0 += 32;
    gld16(&As[sel * 4096 + lA1], pA1); pA1 += 32;
    gld16(&Ba[sel * 2048 + lBc], pBa); pBa += 32;
    gld16(&Bg[sel * 2048 + lBc], pBg); pBg += 32;
  };

  const int NK = DM / 32;
  stage(0);
  for (int kt = 0; kt < NK; kt++) {
    int cur = kt & 1;
    if (kt + 1 < NK) {
      stage(cur ^ 1);
      BAR1_N(4);
    } else {
      BAR1_N(0);
    }
    const bf16* Ab = As + cur * 4096;
    const bf16* Bab = Ba + cur * 2048;
    const bf16* Bgb = Bg + cur * 2048;
    bfrag af[2], ba[4], bg[4];
#pragma unroll
    for (int i = 0; i < 2; i++) {
      int r = w * 32 + i * 16 + l16;
      af[i] = *(const bfrag*)&Ab[r * 32 + (quad ^ ((r >> 1) & 3)) * 8];
    }
#pragma unroll
    for (int j = 0; j < 4; j++) {
      int r = j * 16 + l16;
      int sw = (quad ^ ((r >> 1) & 3)) * 8;
      ba[j] = *(const bfrag*)&Bab[r * 32 + sw];
      bg[j] = *(const bfrag*)&Bgb[r * 32 + sw];
    }
#pragma unroll
    for (int i = 0; i < 2; i++)
#pragma unroll
      for (int j = 0; j < 4; j++) {
        aa[i][j] = __builtin_amdgcn_mfma_f32_16x16x32_bf16(af[i], ba[j], aa[i][j], 0, 0, 0);
        ag[i][j] = __builtin_amdgcn_mfma_f32_16x16x32_bf16(af[i], bg[j], ag[i][j], 0, 0, 0);
      }
    BAR2();
  }
#pragma unroll
  for (int i = 0; i < 2; i++) {
    int mrow = m0 + w * 32 + i * 16 + quad * 4;
#pragma unroll
    for (int j = 0; j < 4; j++) {
      int ncol = n0 + j * 16 + l16;
#pragma unroll
      for (int r = 0; r < 4; r++) {
        float a = aa[i][j][r], g = ag[i][j][r];
        float v = a * g / (1.f + __expf(-g));
        Out[(size_t)(mrow + r) * DFF + ncol] = __float2bfloat16(v);
      }
    }
  }
}

// ---------- cos-scale + RoPE, vectorized: one wave = 8 tokens, lane = (tok,8-chunk) ----------
__device__ __forceinline__ void rope8(const bf16* __restrict__ inp, const float* __restrict__ pos3,
                                      float s, float fr0, int k, int lane,
                                      bf16* __restrict__ outp) {
  bfrag v = *(const bfrag*)inp;
  float x[8];
#pragma unroll
  for (int i = 0; i < 8; i++) x[i] = __bfloat162float(__builtin_bit_cast(bf16, (short)v[i]));
  float ss = 0.f;
#pragma unroll
  for (int i = 0; i < 8; i++) ss += x[i] * x[i];
  ss += __shfl_xor(ss, 1, 64);
  ss += __shfl_xor(ss, 2, 64);
  ss += __shfl_xor(ss, 4, 64);
  float g = s * rsqrtf(ss + 1e-6f);
#pragma unroll
  for (int i = 0; i < 8; i++) x[i] *= g;
  int pk = k < 3 ? k + 3 : (k < 6 ? k - 3 : k);
  int psrc = (lane & 56) | pk;
  float other[8];
#pragma unroll
  for (int i = 0; i < 8; i++) other[i] = __shfl(x[i], psrc, 64);
  bfrag o;
  if (k < 6) {
    int c = k < 3 ? k : k - 3;
    float p = pos3[c];
    float fr = fr0;
    float sgn = k < 3 ? -1.f : 1.f;
#pragma unroll
    for (int i = 0; i < 8; i++) {
      float th = p * fr;
      fr *= 1.333521432163324f; // 10^(1/8)
      float st = __sinf(th), ct = __cosf(th);
      o[i] = __builtin_bit_cast(short, __float2bfloat16(x[i] * ct + sgn * other[i] * st));
    }
  } else {
#pragma unroll
    for (int i = 0; i < 8; i++) o[i] = __builtin_bit_cast(short, __float2bfloat16(x[i]));
  }
  *(bfrag*)outp = o;
}

__global__ __launch_bounds__(256) void k_ropeqk(const bf16* __restrict__ inQ, int strQ, int offQ,
                                                const bf16* __restrict__ inK, int strK, int offK,
                                                const float* __restrict__ posQ,
                                                const float* __restrict__ posK,
                                                const float* __restrict__ scale,
                                                bf16* __restrict__ outQ, bf16* __restrict__ outK) {
  int wid = blockIdx.x * 4 + (threadIdx.x >> 6);
  int lane = threadIdx.x & 63;
  int k = lane & 7;
  int item = wid * 8 + (lane >> 3); // (b*NH + h)*L + l ; bh uniform per wave (8|L)
  int l = item % L;
  int bh = item / L;
  int h = bh % NH;
  int b = bh / NH;
  float s = sqrtf(scale[h]);
  float fr0 = __expf(1.14472988584940017f + (float)h * 0.023985261385354646f);
  size_t tokrow = (size_t)(b * L + l);
  rope8(inQ + tokrow * strQ + offQ + h * DH + k * 8, &posQ[tokrow * 3], s, fr0, k, lane,
        outQ + (size_t)item * DH + k * 8);
  rope8(inK + tokrow * strK + offK + h * DH + k * 8, &posK[tokrow * 3], s, fr0, k, lane,
        outK + (size_t)item * DH + k * 8);
}

// ---------- V transpose: (b,l,h,d)-strided slice -> Vt (bh, DH, L) ----------
// Keys are stored PERMUTED within each 16-token group: slot p holds token
// swap23(p) (bits 2<->3), matching the native key order of QK^T output frags.
__global__ __launch_bounds__(256) void k_vtrans(const bf16* __restrict__ in, int stride, int off,
                                                bf16* __restrict__ Vt) {
  __shared__ __align__(16) bf16 St[64 * 64];
  int lt = blockIdx.x & 31, bh = blockIdx.x >> 5;
  int h = bh % NH, b = bh / NH;
  int t = threadIdx.x;
#pragma unroll
  for (int pass = 0; pass < 2; pass++) {
    int cid = t + pass * 256;
    int r = cid >> 3, c = cid & 7; // token r, d-chunk c
    *(float4*)&St[ASW(r, c)] =
        *(const float4*)&in[(size_t)(b * L + lt * 64 + r) * stride + off + h * DH + c * 8];
  }
  __syncthreads();
  const short* Ss = (const short*)St;
#pragma unroll
  for (int pass = 0; pass < 2; pass++) {
    int cid = t + pass * 256;
    int d = cid >> 3, oc = cid & 7; // out row d, slot-chunk oc
    bfrag tmp;
#pragma unroll
    for (int i = 0; i < 8; i++) {
      int p = oc * 8 + i;
      int tok = (p & ~12) | ((p & 4) << 1) | ((p & 8) >> 1); // swap bits 2,3
      tmp[i] = Ss[(tok << 6) + ((((d >> 3) ^ (tok & 7))) << 3) + (d & 7)];
    }
    *(bfrag*)&Vt[((size_t)bh * DH + d) * L + lt * 64 + oc * 8] = tmp;
  }
}

// ---------- MFMA flash attention, 32x32x16, fixed-bound softmax ----------
// R9 verified structure: P fully in-register (swap23-permuted V); 3-buffer KV
// rotation with a single counted barrier per KV tile. NEW: XCD-chunked block
// remap so each XCD owns whole bh groups (K/V panels single-L2). 768%8==0.
__global__ __launch_bounds__(256) void k_attn_mfma(const bf16* __restrict__ Q,
                                                   const bf16* __restrict__ K,
                                                   const bf16* __restrict__ Vt,
                                                   const float* __restrict__ scale,
                                                   bf16* __restrict__ O) {
  __shared__ __align__(16) char smem[49152 + 512];
  bf16* Ks = (bf16*)smem;               // 3 x 8KB [key][d]
  bf16* Vs = (bf16*)(smem + 24576);     // 3 x 8KB [d][key-permuted]
  float* Oex = (float*)smem;            // 16KB overlay (after final barrier)
  float* Lred = (float*)(smem + 49152); // 2*64
  int orig = blockIdx.x;
  int xcd = orig & 7, idx = orig >> 3;
  int gidx = xcd * ((int)gridDim.x >> 3) + idx;
  int qt = gidx & 31, bh = gidx >> 5;
  int h = bh % NH, b = bh / NH;
  float smax = scale[h];
  float nsl2 = -smax * 1.442695040888963f; // -smax * log2(e)
  int t = threadIdx.x, w = t >> 6, lane = t & 63;
  int hh = lane >> 5, l32 = lane & 31;
  int qsub = w >> 1, ksub = w & 1;

  const bf16* kbase = K + (size_t)(bh * L) * DH;
  const bf16* vbase = Vt + (size_t)bh * DH * L;

  // Q B-frags in registers (q = qsub*32 + l32, d-chunks)
  const bf16* qrow = Q + ((size_t)(bh * L) + qt * 64 + qsub * 32 + l32) * DH;
  bfrag qf[4];
#pragma unroll
  for (int c = 0; c < 4; c++) qf[c] = *(const bfrag*)&qrow[c * 16 + hh * 8];

  facc16 o0, o1;
#pragma unroll
  for (int i = 0; i < 16; i++) { o0[i] = 0.f; o1[i] = 0.f; }
  float l_run = 0.f;

  // hoisted staging pointers: kg += 64*DH, vg += 64 per tile
  const bf16 *kg0, *kg1, *vg0, *vg1;
  int lk0, lk1;
  {
    int r0 = w * 8 + (lane >> 3);
    int kc0 = (lane & 7) ^ (r0 & 7);
    int r1 = r0 + 32;
    int kc1 = (lane & 7) ^ (r1 & 7);
    kg0 = kbase + (size_t)r0 * DH + kc0 * 8;
    kg1 = kbase + (size_t)r1 * DH + kc1 * 8;
    vg0 = vbase + (size_t)r0 * L + kc0 * 8;
    vg1 = vbase + (size_t)r1 * L + kc1 * 8;
    lk0 = (w * 8) * 64 + lane * 8;
    lk1 = (w * 8 + 32) * 64 + lane * 8;
  }
  auto stageKV = [&](int sel) {
    gld16(&Ks[sel * 4096 + lk0], kg0); kg0 += 64 * DH;
    gld16(&Ks[sel * 4096 + lk1], kg1); kg1 += 64 * DH;
    gld16(&Vs[sel * 4096 + lk0], vg0); vg0 += 64;
    gld16(&Vs[sel * 4096 + lk1], vg1); vg1 += 64;
  };

  stageKV(0);
  stageKV(1);
  int cur = 0;
  for (int kt = 0; kt < 32; kt++) {
    if (kt < 31) { BAR1_N(4); } else { BAR1_N(0); } // tile kt ready
    if (kt + 2 < 32) {
      int nb = cur + 2; if (nb >= 3) nb -= 3;
      stageKV(nb); // writes buf (kt-1)%3: its readers finished pre-barrier
    }
    const bf16* Kb = Ks + cur * 4096;
    const bf16* Vb = Vs + cur * 4096;
    // ---- S^T = K·Q^T (m=key 32 of ksub, n=q 32 of qsub, k=d 64) ----
    facc16 s;
#pragma unroll
    for (int i = 0; i < 16; i++) s[i] = 0.f;
#pragma unroll
    for (int c = 0; c < 4; c++) {
      bfrag kf = *(const bfrag*)&Kb[ASW(ksub * 32 + l32, c * 2 + hh)];
      s = __builtin_amdgcn_mfma_f32_32x32x16_bf16(kf, qf[c], s, 0, 0, 0);
    }
    // ---- p = exp2(s*log2e - smax*log2e); lane holds P[q=l32][16 keys] ----
    float pv[16];
#pragma unroll
    for (int reg = 0; reg < 16; reg++) {
      float p = __builtin_amdgcn_exp2f(__builtin_fmaf(s[reg], 1.442695040888963f, nsl2));
      l_run += p;
      pv[reg] = p;
    }
    // ---- pack P directly into A-frags (native key order = swap23 slots) ----
    bfrag pf0, pf1;
#pragma unroll
    for (int j = 0; j < 8; j++) {
      pf0[j] = __builtin_bit_cast(short, __float2bfloat16(pv[j]));
      pf1[j] = __builtin_bit_cast(short, __float2bfloat16(pv[8 + j]));
    }
    // ---- O partial += P(own keys) · V (V stored key-permuted to match) ----
    {
      bfrag vf;
      vf = *(const bfrag*)&Vb[ASW(l32, ksub * 4 + hh)];
      o0 = __builtin_amdgcn_mfma_f32_32x32x16_bf16(pf0, vf, o0, 0, 0, 0);
      vf = *(const bfrag*)&Vb[ASW(l32, ksub * 4 + 2 + hh)];
      o0 = __builtin_amdgcn_mfma_f32_32x32x16_bf16(pf1, vf, o0, 0, 0, 0);
      vf = *(const bfrag*)&Vb[ASW(32 + l32, ksub * 4 + hh)];
      o1 = __builtin_amdgcn_mfma_f32_32x32x16_bf16(pf0, vf, o1, 0, 0, 0);
      vf = *(const bfrag*)&Vb[ASW(32 + l32, ksub * 4 + 2 + hh)];
      o1 = __builtin_amdgcn_mfma_f32_32x32x16_bf16(pf1, vf, o1, 0, 0, 0);
    }
    cur = (cur == 2) ? 0 : cur + 1;
  }
  // ---- merge halves of l (keys split across lane halves) ----
  l_run += __shfl_xor(l_run, 32, 64);
  __syncthreads(); // all PV reads done; Ks/Vs reusable as Oex
  {
    int gd = (ksub ^ 1) * 32 + l32;
#pragma unroll
    for (int reg = 0; reg < 16; reg++) {
      int row = (reg & 3) + 8 * (reg >> 2) + 4 * hh;
      float gv = ksub ? o0[reg] : o1[reg];
      Oex[(size_t)(qsub * 32 + row) * 64 + gd] = gv;
    }
  }
  if (lane < 32) Lred[ksub * 64 + qsub * 32 + lane] = l_run;
  __syncthreads();
  {
    int d = ksub * 32 + l32;
#pragma unroll
    for (int reg = 0; reg < 16; reg++) {
      int row = (reg & 3) + 8 * (reg >> 2) + 4 * hh;
      int qg2 = qsub * 32 + row;
      float ltot = Lred[qg2] + Lred[64 + qg2];
      float keep = ksub ? o1[reg] : o0[reg];
      float v = (keep + Oex[(size_t)qg2 * 64 + d]) / ltot;
      O[(((size_t)(b * L) + qt * 64 + qg2) * NH + h) * DH + d] = __float2bfloat16(v);
    }
  }
}

extern "C" void kernel_launch(void* const* d_in, const int* in_sizes, int n_in,
                              void* d_out, int out_size, void* d_ws, size_t ws_size,
                              hipStream_t stream) {
  const float* x = (const float*)d_in[0];
  const float* pos = (const float*)d_in[1];
  const float* x_cross = (const float*)d_in[2];
  const float* pos_cross = (const float*)d_in[3];
  const float* sa_norm_scale = (const float*)d_in[4];
  const float* sa_wqkv = (const float*)d_in[5];
  const float* sa_scale = (const float*)d_in[6];
  const float* sa_wout = (const float*)d_in[7];
  const float* ca_norm_scale = (const float*)d_in[8];
  const float* ca_norm_cross_scale = (const float*)d_in[9];
  const float* ca_wq = (const float*)d_in[10];
  const float* ca_wkv = (const float*)d_in[11];
  const float* ca_scale = (const float*)d_in[12];
  const float* ca_wout = (const float*)d_in[13];
  const float* ff_norm_scale = (const float*)d_in[14];
  const float* ff_wup = (const float*)d_in[15];
  const float* ff_wdown = (const float*)d_in[16];
  float* out = (float*)d_out;

  float* ws = (float*)d_ws;
  const size_t S = (size_t)M_TOK * DM; // 3,145,728
  float* xbuf = ws; // S f32: running residual
  bf16* b16 = (bf16*)(ws + S);
  bf16* qkvb = b16;        // 3S: qkv (self) / caq + cakv (cross) / ffact (FF)
  bf16* qb = b16 + 3 * S;  // (BH, L, DH)
  bf16* kb = b16 + 4 * S;  // (BH, L, DH)
  bf16* vtb = b16 + 5 * S; // (BH, DH, L) key-permuted
  bf16* hb = b16 + 6 * S;
  bf16* hcb = b16 + 7 * S;
  bf16* obb = b16 + 8 * S; // attn out (B,L,NH,DH)
  bf16* wqkvb = b16 + 9 * S; // weight arena: 17*DM*DM contiguous, castall order
  bf16* woutb = wqkvb + (size_t)3 * DM * DM;
  bf16* wqb = woutb + (size_t)DM * DM;
  bf16* wkvb = wqb + (size_t)DM * DM;
  bf16* wout2b = wkvb + (size_t)2 * DM * DM;
  bf16* wupb = wout2b + (size_t)DM * DM;
  bf16* wdownb = wupb + (size_t)2 * DFF * DM;
  bf16* ffb = qkvb;

  const int ropeGrid = B * NH * L / 32; // 8 tokens/wave, 4 waves/block
  const int attnGrid = B * NH * (L / 64); // 768
  const int vtGrid = B * NH * (L / 64);   // 768
  const size_t DM2 = (size_t)DM * DM;
  const int castGrid = (int)((17 * DM2 / 4 + 255) / 256);

  k_castall<<<castGrid, 256, 0, stream>>>(sa_wqkv, sa_wout, ca_wq, ca_wkv, ca_wout, ff_wup,
                                          ff_wdown, wqkvb);

  // ---- merged prologue norms: self (x) + cross (x_cross) ----
  k_rmsnorm2<<<2 * M_TOK, 256, 0, stream>>>(x, sa_norm_scale, hb, x_cross, ca_norm_cross_scale,
                                            hcb);

  // ---- self attention ----
  k_gemm<128, 1><<<dim3(3 * DM / 128, M_TOK / 128), 256, 0, stream>>>(
      hb, wqkvb, nullptr, qkvb, nullptr, M_TOK, 3 * DM, DM);
  k_ropeqk<<<ropeGrid, 256, 0, stream>>>(qkvb, 3 * DM, 0, qkvb, 3 * DM, DM, pos, pos, sa_scale,
                                         qb, kb);
  k_vtrans<<<vtGrid, 256, 0, stream>>>(qkvb, 3 * DM, 2 * DM, vtb);
  k_attn_mfma<<<attnGrid, 256, 0, stream>>>(qb, kb, vtb, sa_scale, obb);
  k_gemm<64, 0><<<dim3(DM / 64, M_TOK / 128), 256, 0, stream>>>(
      obb, woutb, xbuf, nullptr, x, M_TOK, DM, DM); // xbuf = attn@wout + x

  // ---- cross attention ----
  k_rmsnorm<<<M_TOK, 256, 0, stream>>>(xbuf, ca_norm_scale, hb);
  k_gemm<64, 1><<<dim3(DM / 64, M_TOK / 128), 256, 0, stream>>>(
      hb, wqb, nullptr, qkvb, nullptr, M_TOK, DM, DM);
  k_gemm<128, 1><<<dim3(2 * DM / 128, M_TOK / 128), 256, 0, stream>>>(
      hcb, wkvb, nullptr, qkvb + S, nullptr, M_TOK, 2 * DM, DM);
  k_ropeqk<<<ropeGrid, 256, 0, stream>>>(qkvb, DM, 0, qkvb + S, 2 * DM, 0, pos, pos_cross,
                                         ca_scale, qb, kb);
  k_vtrans<<<vtGrid, 256, 0, stream>>>(qkvb + S, 2 * DM, DM, vtb);
  k_attn_mfma<<<attnGrid, 256, 0, stream>>>(qb, kb, vtb, ca_scale, obb);
  k_gemm<64, 0><<<dim3(DM / 64, M_TOK / 128), 256, 0, stream>>>(
      obb, wout2b, xbuf, nullptr, xbuf, M_TOK, DM, DM);

  // ---- feed-forward (fused up+SwiGLU, then down) ----
  k_rmsnorm<<<M_TOK, 256, 0, stream>>>(xbuf, ff_norm_scale, hb);
  k_ffup<<<dim3(DFF / 64, M_TOK / 128), 256, 0, stream>>>(hb, wupb, ffb);
  k_gemm<64, 0><<<dim3(DM / 64, M_TOK / 128), 256, 0, stream>>>(
      ffb, wdownb, out, nullptr, xbuf, M_TOK, DM, DFF);
}

// Round 12
// 425.644 us; speedup vs baseline: 1.0534x; 1.0018x over previous
//
#include <hip/hip_runtime.h>
#include <hip/hip_bf16.h>
#include <math.h>

typedef __hip_bfloat16 bf16;

#define B 2
#define L 2048
#define DM 768
#define NH 12
#define DH 64
#define DFF 2304
#define M_TOK (B * L) // 4096

typedef __attribute__((ext_vector_type(8))) short bfrag;
typedef __attribute__((ext_vector_type(4))) float ffrag;
typedef __attribute__((ext_vector_type(16))) float facc16;

__device__ __forceinline__ float waveSum(float v) {
#pragma unroll
  for (int o = 32; o > 0; o >>= 1) v += __shfl_down(v, o, 64);
  return v;
}

__device__ __forceinline__ void gld16(void* l, const void* g) {
  __builtin_amdgcn_global_load_lds((const __attribute__((address_space(1))) unsigned*)g,
                                   (__attribute__((address_space(3))) unsigned*)l, 16, 0, 0);
}

// counted-vmcnt barrier pair (T3/T4 minimum form, m201 pattern):
// BAR1(N): wait own tile's loads (leave newer tiles' N in flight), then barrier.
// BAR2: drain ds_reads (protect buffer overwrite), then barrier.
// NOTE: N must be a LITERAL (stringized into asm) -- dispatch constexpr values
// via if constexpr at the call site.
#define BAR1_N(N) do { asm volatile("s_waitcnt vmcnt(" #N ")" ::: "memory"); \
                       __builtin_amdgcn_s_barrier(); } while (0)
#define BAR2() do { asm volatile("s_waitcnt lgkmcnt(0)" ::: "memory"); \
                    __builtin_amdgcn_s_barrier(); } while (0)

// element-index swizzle for 64-col bf16 LDS tiles (16B chunk XOR row&7)
#define ASW(row, chunk) (((row) << 6) + ((((chunk) ^ ((row)&7))) << 3))

// ---------- fused weight cast fp32 -> bf16 (7 segments, contiguous dst arena) ----------
__global__ void k_castall(const float* __restrict__ s0, const float* __restrict__ s1,
                          const float* __restrict__ s2, const float* __restrict__ s3,
                          const float* __restrict__ s4, const float* __restrict__ s5,
                          const float* __restrict__ s6, bf16* __restrict__ dst) {
  const size_t DM2 = (size_t)DM * DM;
  size_t u = ((size_t)blockIdx.x * 256 + threadIdx.x) * 4;
  if (u >= 17 * DM2) return;
  const float* src;
  size_t loc;
  if (u < 3 * DM2) { src = s0; loc = u; }
  else if (u < 4 * DM2) { src = s1; loc = u - 3 * DM2; }
  else if (u < 5 * DM2) { src = s2; loc = u - 4 * DM2; }
  else if (u < 7 * DM2) { src = s3; loc = u - 5 * DM2; }
  else if (u < 8 * DM2) { src = s4; loc = u - 7 * DM2; }
  else if (u < 14 * DM2) { src = s5; loc = u - 8 * DM2; }
  else { src = s6; loc = u - 14 * DM2; }
  float4 v = *(const float4*)&src[loc];
  bf16* d = dst + u;
  d[0] = __float2bfloat16(v.x);
  d[1] = __float2bfloat16(v.y);
  d[2] = __float2bfloat16(v.z);
  d[3] = __float2bfloat16(v.w);
}

// ---------- RMSNorm: one block (256 thr) per row of 768; bf16 out ----------
__device__ __forceinline__ void rms_body(const float* __restrict__ in,
                                         const float* __restrict__ scale, int row, int t,
                                         bf16* __restrict__ out) {
  const float* r = in + (size_t)row * DM;
  float x0 = r[t], x1 = r[t + 256], x2 = r[t + 512];
  float ss = x0 * x0 + x1 * x1 + x2 * x2;
  ss = waveSum(ss);
  __shared__ float red[4];
  int w = t >> 6, ln = t & 63;
  if (ln == 0) red[w] = ss;
  __syncthreads();
  float tot = red[0] + red[1] + red[2] + red[3];
  float g = rsqrtf(tot / (float)DM + 1e-6f);
  bf16* o = out + (size_t)row * DM;
  o[t] = __float2bfloat16(x0 * g * scale[t]);
  o[t + 256] = __float2bfloat16(x1 * g * scale[t + 256]);
  o[t + 512] = __float2bfloat16(x2 * g * scale[t + 512]);
}

__global__ __launch_bounds__(256) void k_rmsnorm(const float* __restrict__ in,
                                                 const float* __restrict__ scale,
                                                 bf16* __restrict__ out) {
  rms_body(in, scale, blockIdx.x, threadIdx.x, out);
}

// two independent rmsnorms in one dispatch (x and x_cross prologue)
__global__ __launch_bounds__(256) void k_rmsnorm2(const float* __restrict__ in0,
                                                  const float* __restrict__ sc0,
                                                  bf16* __restrict__ out0,
                                                  const float* __restrict__ in1,
                                                  const float* __restrict__ sc1,
                                                  bf16* __restrict__ out1) {
  int row = blockIdx.x;
  if (row < M_TOK) rms_body(in0, sc0, row, threadIdx.x, out0);
  else rms_body(in1, sc1, row - M_TOK, threadIdx.x, out1);
}

// ---------- MFMA GEMM, BK=64 double-buffered K-loop, counted-vmcnt barriers ----------
// 32 MFMA per wave per barrier pair; 64-col LDS rows w/ ASW swizzle (R8 proven).
// XCD-chunked block remap (T1): each of 8 XCDs owns a contiguous m-range.
// Per-XCD working set (4 A-panels + all W n-panels) fits the 4MB L2 at these
// shapes (<=3.5MB) -- R11 measured the family gain. (ffup is the exception:
// its 6.9MB weight set thrashes, so ffup keeps identity mapping.)
template <int NT, int OBF>
__global__ __launch_bounds__(256) void k_gemm(const bf16* __restrict__ A,
                                              const bf16* __restrict__ W,
                                              float* __restrict__ C,
                                              bf16* __restrict__ Cb,
                                              const float* __restrict__ res,
                                              int M, int N, int K) {
  __shared__ __align__(16) bf16 As[2 * 128 * 64];
  __shared__ __align__(16) bf16 Bs[2 * NT * 64];
  const int t = threadIdx.x;
  const int w = t >> 6, lane = t & 63;
  int orig = blockIdx.y * gridDim.x + blockIdx.x;
  int xcd = orig & 7, idx = orig >> 3;
  int mchunk = gridDim.y >> 3; // 4 (gridDim.y == 32 at every call site)
  int my = xcd * mchunk + idx / gridDim.x;
  int nx = idx % gridDim.x;
  const int m0 = my * 128, n0 = nx * NT;
  const int quad = lane >> 4, l16 = lane & 15;
  constexpr int MI = (NT == 128) ? 4 : 2;
  const int wrow = (NT == 128) ? (w >> 1) * 64 : w * 32;
  const int wcol = (NT == 128) ? (w & 1) * 64 : 0;

  ffrag acc[MI][4];
#pragma unroll
  for (int i = 0; i < MI; i++)
#pragma unroll
    for (int j = 0; j < 4; j++) acc[i][j] = (ffrag){0.f, 0.f, 0.f, 0.f};

  // hoisted staging pointers (advance 64 elems per staged K-tile)
  const bf16 *pA[4], *pB[4];
  int lA[4], lB[4];
#pragma unroll
  for (int it = 0; it < 4; it++) {
    int lc = (w * 4 + it) * 64 + lane;
    int r = lc >> 3, c = lc & 7, kc = c ^ (r & 7);
    pA[it] = A + (size_t)(m0 + r) * K + kc * 8;
    lA[it] = lc * 8;
  }
  if (NT == 128) {
#pragma unroll
    for (int it = 0; it < 4; it++) {
      int lc = (w * 4 + it) * 64 + lane;
      int r = lc >> 3, c = lc & 7, kc = c ^ (r & 7);
      pB[it] = W + (size_t)(n0 + r) * K + kc * 8;
      lB[it] = lc * 8;
    }
  } else {
#pragma unroll
    for (int it = 0; it < 2; it++) {
      int lc = (w * 2 + it) * 64 + lane;
      int r = lc >> 3, c = lc & 7, kc = c ^ (r & 7);
      pB[it] = W + (size_t)(n0 + r) * K + kc * 8;
      lB[it] = lc * 8;
    }
  }
  auto stage = [&](int sel) {
#pragma unroll
    for (int it = 0; it < 4; it++) { gld16(&As[sel * 8192 + lA[it]], pA[it]); pA[it] += 64; }
    if (NT == 128) {
#pragma unroll
      for (int it = 0; it < 4; it++) { gld16(&Bs[sel * 8192 + lB[it]], pB[it]); pB[it] += 64; }
    } else {
#pragma unroll
      for (int it = 0; it < 2; it++) { gld16(&Bs[sel * 4096 + lB[it]], pB[it]); pB[it] += 64; }
    }
  };

  const int NK = K >> 6; // 12 or 36
  stage(0);
  for (int kt = 0; kt < NK; kt++) {
    int cur = kt & 1;
    if (kt + 1 < NK) {
      stage(cur ^ 1);
      if constexpr (NT == 128) { BAR1_N(8); } else { BAR1_N(6); }
    } else {
      BAR1_N(0);
    }
    const bf16* Ab = As + cur * 8192;
    const bf16* Bb = Bs + cur * (NT == 128 ? 8192 : 4096);
#pragma unroll
    for (int s = 0; s < 2; s++) {
      bfrag af[MI], bfv[4];
#pragma unroll
      for (int i = 0; i < MI; i++)
        af[i] = *(const bfrag*)&Ab[ASW(wrow + i * 16 + l16, s * 4 + quad)];
#pragma unroll
      for (int j = 0; j < 4; j++)
        bfv[j] = *(const bfrag*)&Bb[ASW(wcol + j * 16 + l16, s * 4 + quad)];
#pragma unroll
      for (int i = 0; i < MI; i++)
#pragma unroll
        for (int j = 0; j < 4; j++)
          acc[i][j] = __builtin_amdgcn_mfma_f32_16x16x32_bf16(af[i], bfv[j], acc[i][j], 0, 0, 0);
    }
    BAR2();
  }
#pragma unroll
  for (int i = 0; i < MI; i++) {
    int mrow = m0 + wrow + i * 16 + quad * 4;
#pragma unroll
    for (int j = 0; j < 4; j++) {
      int ncol = n0 + wcol + j * 16 + l16;
#pragma unroll
      for (int r = 0; r < 4; r++) {
        float v = acc[i][j][r];
        size_t idx2 = (size_t)(mrow + r) * N + ncol;
        if (OBF) {
          Cb[idx2] = __float2bfloat16(v);
        } else {
          if (res) v += res[idx2];
          C[idx2] = v;
        }
      }
    }
  }
}

// ---------- fused ff_up + SwiGLU, BK=32 (R5 proven config, IDENTITY mapping) ----------
// No XCD remap here: ffup's weight working set (36 n-panels x 192KB = 6.9MB)
// exceeds the 4MB per-XCD L2, so m-chunking thrashes (R11: FETCH 38.8->59MB).
__global__ __launch_bounds__(256) void k_ffup(const bf16* __restrict__ A,
                                              const bf16* __restrict__ Wup,
                                              bf16* __restrict__ Out) {
  __shared__ __align__(16) bf16 As[2 * 128 * 32];
  __shared__ __align__(16) bf16 Ba[2 * 64 * 32];
  __shared__ __align__(16) bf16 Bg[2 * 64 * 32];
  const int t = threadIdx.x, w = t >> 6, lane = t & 63;
  const int m0 = blockIdx.y * 128, n0 = blockIdx.x * 64;
  const int quad = lane >> 4, l16 = lane & 15;

  ffrag aa[2][4], ag[2][4];
#pragma unroll
  for (int i = 0; i < 2; i++)
#pragma unroll
    for (int j = 0; j < 4; j++) {
      aa[i][j] = (ffrag){0.f, 0.f, 0.f, 0.f};
      ag[i][j] = (ffrag){0.f, 0.f, 0.f, 0.f};
    }

  const bf16 *pA0, *pA1, *pBa, *pBg;
  int lA0, lA1, lBc;
  {
    int lc0 = (w * 2 + 0) * 64 + lane;
    int r0 = lc0 >> 2, kc0 = (lc0 & 3) ^ ((r0 >> 1) & 3);
    int lc1 = (w * 2 + 1) * 64 + lane;
    int r1 = lc1 >> 2, kc1 = (lc1 & 3) ^ ((r1 >> 1) & 3);
    pA0 = A + (size_t)(m0 + r0) * DM + kc0 * 8; lA0 = lc0 * 8;
    pA1 = A + (size_t)(m0 + r1) * DM + kc1 * 8; lA1 = lc1 * 8;
    int lc = w * 64 + lane;
    int r = lc >> 2, kc = (lc & 3) ^ ((r >> 1) & 3);
    pBa = Wup + (size_t)(n0 + r) * DM + kc * 8;
    pBg = Wup + (size_t)(DFF + n0 + r) * DM + kc * 8;
    lBc = lc * 8;
  }
  auto stage = [&](int sel) {
    gld16(&As[sel * 4096 + lA0], pA0); pA0 += 32;
    gld16(&As[sel * 4096 + lA1], pA1); pA1 += 32;
    gld16(&Ba[sel * 2048 + lBc], pBa); pBa += 32;
    gld16(&Bg[sel * 2048 + lBc], pBg); pBg += 32;
  };

  const int NK = DM / 32;
  stage(0);
  for (int kt = 0; kt < NK; kt++) {
    int cur = kt & 1;
    if (kt + 1 < NK) {
      stage(cur ^ 1);
      BAR1_N(4);
    } else {
      BAR1_N(0);
    }
    const bf16* Ab = As + cur * 4096;
    const bf16* Bab = Ba + cur * 2048;
    const bf16* Bgb = Bg + cur * 2048;
    bfrag af[2], ba[4], bg[4];
#pragma unroll
    for (int i = 0; i < 2; i++) {
      int r = w * 32 + i * 16 + l16;
      af[i] = *(const bfrag*)&Ab[r * 32 + (quad ^ ((r >> 1) & 3)) * 8];
    }
#pragma unroll
    for (int j = 0; j < 4; j++) {
      int r = j * 16 + l16;
      int sw = (quad ^ ((r >> 1) & 3)) * 8;
      ba[j] = *(const bfrag*)&Bab[r * 32 + sw];
      bg[j] = *(const bfrag*)&Bgb[r * 32 + sw];
    }
#pragma unroll
    for (int i = 0; i < 2; i++)
#pragma unroll
      for (int j = 0; j < 4; j++) {
        aa[i][j] = __builtin_amdgcn_mfma_f32_16x16x32_bf16(af[i], ba[j], aa[i][j], 0, 0, 0);
        ag[i][j] = __builtin_amdgcn_mfma_f32_16x16x32_bf16(af[i], bg[j], ag[i][j], 0, 0, 0);
      }
    BAR2();
  }
#pragma unroll
  for (int i = 0; i < 2; i++) {
    int mrow = m0 + w * 32 + i * 16 + quad * 4;
#pragma unroll
    for (int j = 0; j < 4; j++) {
      int ncol = n0 + j * 16 + l16;
#pragma unroll
      for (int r = 0; r < 4; r++) {
        float a = aa[i][j][r], g = ag[i][j][r];
        float v = a * g / (1.f + __expf(-g));
        Out[(size_t)(mrow + r) * DFF + ncol] = __float2bfloat16(v);
      }
    }
  }
}

// ---------- cos-scale + RoPE, vectorized: one wave = 8 tokens, lane = (tok,8-chunk) ----------
__device__ __forceinline__ void rope8(const bf16* __restrict__ inp, const float* __restrict__ pos3,
                                      float s, float fr0, int k, int lane,
                                      bf16* __restrict__ outp) {
  bfrag v = *(const bfrag*)inp;
  float x[8];
#pragma unroll
  for (int i = 0; i < 8; i++) x[i] = __bfloat162float(__builtin_bit_cast(bf16, (short)v[i]));
  float ss = 0.f;
#pragma unroll
  for (int i = 0; i < 8; i++) ss += x[i] * x[i];
  ss += __shfl_xor(ss, 1, 64);
  ss += __shfl_xor(ss, 2, 64);
  ss += __shfl_xor(ss, 4, 64);
  float g = s * rsqrtf(ss + 1e-6f);
#pragma unroll
  for (int i = 0; i < 8; i++) x[i] *= g;
  int pk = k < 3 ? k + 3 : (k < 6 ? k - 3 : k);
  int psrc = (lane & 56) | pk;
  float other[8];
#pragma unroll
  for (int i = 0; i < 8; i++) other[i] = __shfl(x[i], psrc, 64);
  bfrag o;
  if (k < 6) {
    int c = k < 3 ? k : k - 3;
    float p = pos3[c];
    float fr = fr0;
    float sgn = k < 3 ? -1.f : 1.f;
#pragma unroll
    for (int i = 0; i < 8; i++) {
      float th = p * fr;
      fr *= 1.333521432163324f; // 10^(1/8)
      float st = __sinf(th), ct = __cosf(th);
      o[i] = __builtin_bit_cast(short, __float2bfloat16(x[i] * ct + sgn * other[i] * st));
    }
  } else {
#pragma unroll
    for (int i = 0; i < 8; i++) o[i] = __builtin_bit_cast(short, __float2bfloat16(x[i]));
  }
  *(bfrag*)outp = o;
}

__global__ __launch_bounds__(256) void k_ropeqk(const bf16* __restrict__ inQ, int strQ, int offQ,
                                                const bf16* __restrict__ inK, int strK, int offK,
                                                const float* __restrict__ posQ,
                                                const float* __restrict__ posK,
                                                const float* __restrict__ scale,
                                                bf16* __restrict__ outQ, bf16* __restrict__ outK) {
  int wid = blockIdx.x * 4 + (threadIdx.x >> 6);
  int lane = threadIdx.x & 63;
  int k = lane & 7;
  int item = wid * 8 + (lane >> 3); // (b*NH + h)*L + l ; bh uniform per wave (8|L)
  int l = item % L;
  int bh = item / L;
  int h = bh % NH;
  int b = bh / NH;
  float s = sqrtf(scale[h]);
  float fr0 = __expf(1.14472988584940017f + (float)h * 0.023985261385354646f);
  size_t tokrow = (size_t)(b * L + l);
  rope8(inQ + tokrow * strQ + offQ + h * DH + k * 8, &posQ[tokrow * 3], s, fr0, k, lane,
        outQ + (size_t)item * DH + k * 8);
  rope8(inK + tokrow * strK + offK + h * DH + k * 8, &posK[tokrow * 3], s, fr0, k, lane,
        outK + (size_t)item * DH + k * 8);
}

// ---------- V transpose: (b,l,h,d)-strided slice -> Vt (bh, DH, L) ----------
// Keys are stored PERMUTED within each 16-token group: slot p holds token
// swap23(p) (bits 2<->3), matching the native key order of QK^T output frags.
__global__ __launch_bounds__(256) void k_vtrans(const bf16* __restrict__ in, int stride, int off,
                                                bf16* __restrict__ Vt) {
  __shared__ __align__(16) bf16 St[64 * 64];
  int lt = blockIdx.x & 31, bh = blockIdx.x >> 5;
  int h = bh % NH, b = bh / NH;
  int t = threadIdx.x;
#pragma unroll
  for (int pass = 0; pass < 2; pass++) {
    int cid = t + pass * 256;
    int r = cid >> 3, c = cid & 7; // token r, d-chunk c
    *(float4*)&St[ASW(r, c)] =
        *(const float4*)&in[(size_t)(b * L + lt * 64 + r) * stride + off + h * DH + c * 8];
  }
  __syncthreads();
  const short* Ss = (const short*)St;
#pragma unroll
  for (int pass = 0; pass < 2; pass++) {
    int cid = t + pass * 256;
    int d = cid >> 3, oc = cid & 7; // out row d, slot-chunk oc
    bfrag tmp;
#pragma unroll
    for (int i = 0; i < 8; i++) {
      int p = oc * 8 + i;
      int tok = (p & ~12) | ((p & 4) << 1) | ((p & 8) >> 1); // swap bits 2,3
      tmp[i] = Ss[(tok << 6) + ((((d >> 3) ^ (tok & 7))) << 3) + (d & 7)];
    }
    *(bfrag*)&Vt[((size_t)bh * DH + d) * L + lt * 64 + oc * 8] = tmp;
  }
}

// ---------- MFMA flash attention, 32x32x16, fixed-bound softmax ----------
// R9 verified structure: P fully in-register (swap23-permuted V); 3-buffer KV
// rotation with a single counted barrier per KV tile. XCD-chunked block
// remap so each XCD owns whole bh groups (K/V panels single-L2, ~0.5MB/bh
// fits). 768%8==0.
__global__ __launch_bounds__(256) void k_attn_mfma(const bf16* __restrict__ Q,
                                                   const bf16* __restrict__ K,
                                                   const bf16* __restrict__ Vt,
                                                   const float* __restrict__ scale,
                                                   bf16* __restrict__ O) {
  __shared__ __align__(16) char smem[49152 + 512];
  bf16* Ks = (bf16*)smem;               // 3 x 8KB [key][d]
  bf16* Vs = (bf16*)(smem + 24576);     // 3 x 8KB [d][key-permuted]
  float* Oex = (float*)smem;            // 16KB overlay (after final barrier)
  float* Lred = (float*)(smem + 49152); // 2*64
  int orig = blockIdx.x;
  int xcd = orig & 7, idx = orig >> 3;
  int gidx = xcd * ((int)gridDim.x >> 3) + idx;
  int qt = gidx & 31, bh = gidx >> 5;
  int h = bh % NH, b = bh / NH;
  float smax = scale[h];
  float nsl2 = -smax * 1.442695040888963f; // -smax * log2(e)
  int t = threadIdx.x, w = t >> 6, lane = t & 63;
  int hh = lane >> 5, l32 = lane & 31;
  int qsub = w >> 1, ksub = w & 1;

  const bf16* kbase = K + (size_t)(bh * L) * DH;
  const bf16* vbase = Vt + (size_t)bh * DH * L;

  // Q B-frags in registers (q = qsub*32 + l32, d-chunks)
  const bf16* qrow = Q + ((size_t)(bh * L) + qt * 64 + qsub * 32 + l32) * DH;
  bfrag qf[4];
#pragma unroll
  for (int c = 0; c < 4; c++) qf[c] = *(const bfrag*)&qrow[c * 16 + hh * 8];

  facc16 o0, o1;
#pragma unroll
  for (int i = 0; i < 16; i++) { o0[i] = 0.f; o1[i] = 0.f; }
  float l_run = 0.f;

  // hoisted staging pointers: kg += 64*DH, vg += 64 per tile
  const bf16 *kg0, *kg1, *vg0, *vg1;
  int lk0, lk1;
  {
    int r0 = w * 8 + (lane >> 3);
    int kc0 = (lane & 7) ^ (r0 & 7);
    int r1 = r0 + 32;
    int kc1 = (lane & 7) ^ (r1 & 7);
    kg0 = kbase + (size_t)r0 * DH + kc0 * 8;
    kg1 = kbase + (size_t)r1 * DH + kc1 * 8;
    vg0 = vbase + (size_t)r0 * L + kc0 * 8;
    vg1 = vbase + (size_t)r1 * L + kc1 * 8;
    lk0 = (w * 8) * 64 + lane * 8;
    lk1 = (w * 8 + 32) * 64 + lane * 8;
  }
  auto stageKV = [&](int sel) {
    gld16(&Ks[sel * 4096 + lk0], kg0); kg0 += 64 * DH;
    gld16(&Ks[sel * 4096 + lk1], kg1); kg1 += 64 * DH;
    gld16(&Vs[sel * 4096 + lk0], vg0); vg0 += 64;
    gld16(&Vs[sel * 4096 + lk1], vg1); vg1 += 64;
  };

  stageKV(0);
  stageKV(1);
  int cur = 0;
  for (int kt = 0; kt < 32; kt++) {
    if (kt < 31) { BAR1_N(4); } else { BAR1_N(0); } // tile kt ready
    if (kt + 2 < 32) {
      int nb = cur + 2; if (nb >= 3) nb -= 3;
      stageKV(nb); // writes buf (kt-1)%3: its readers finished pre-barrier
    }
    const bf16* Kb = Ks + cur * 4096;
    const bf16* Vb = Vs + cur * 4096;
    // ---- S^T = K·Q^T (m=key 32 of ksub, n=q 32 of qsub, k=d 64) ----
    facc16 s;
#pragma unroll
    for (int i = 0; i < 16; i++) s[i] = 0.f;
#pragma unroll
    for (int c = 0; c < 4; c++) {
      bfrag kf = *(const bfrag*)&Kb[ASW(ksub * 32 + l32, c * 2 + hh)];
      s = __builtin_amdgcn_mfma_f32_32x32x16_bf16(kf, qf[c], s, 0, 0, 0);
    }
    // ---- p = exp2(s*log2e - smax*log2e); lane holds P[q=l32][16 keys] ----
    float pv[16];
#pragma unroll
    for (int reg = 0; reg < 16; reg++) {
      float p = __builtin_amdgcn_exp2f(__builtin_fmaf(s[reg], 1.442695040888963f, nsl2));
      l_run += p;
      pv[reg] = p;
    }
    // ---- pack P directly into A-frags (native key order = swap23 slots) ----
    bfrag pf0, pf1;
#pragma unroll
    for (int j = 0; j < 8; j++) {
      pf0[j] = __builtin_bit_cast(short, __float2bfloat16(pv[j]));
      pf1[j] = __builtin_bit_cast(short, __float2bfloat16(pv[8 + j]));
    }
    // ---- O partial += P(own keys) · V (V stored key-permuted to match) ----
    {
      bfrag vf;
      vf = *(const bfrag*)&Vb[ASW(l32, ksub * 4 + hh)];
      o0 = __builtin_amdgcn_mfma_f32_32x32x16_bf16(pf0, vf, o0, 0, 0, 0);
      vf = *(const bfrag*)&Vb[ASW(l32, ksub * 4 + 2 + hh)];
      o0 = __builtin_amdgcn_mfma_f32_32x32x16_bf16(pf1, vf, o0, 0, 0, 0);
      vf = *(const bfrag*)&Vb[ASW(32 + l32, ksub * 4 + hh)];
      o1 = __builtin_amdgcn_mfma_f32_32x32x16_bf16(pf0, vf, o1, 0, 0, 0);
      vf = *(const bfrag*)&Vb[ASW(32 + l32, ksub * 4 + 2 + hh)];
      o1 = __builtin_amdgcn_mfma_f32_32x32x16_bf16(pf1, vf, o1, 0, 0, 0);
    }
    cur = (cur == 2) ? 0 : cur + 1;
  }
  // ---- merge halves of l (keys split across lane halves) ----
  l_run += __shfl_xor(l_run, 32, 64);
  __syncthreads(); // all PV reads done; Ks/Vs reusable as Oex
  {
    int gd = (ksub ^ 1) * 32 + l32;
#pragma unroll
    for (int reg = 0; reg < 16; reg++) {
      int row = (reg & 3) + 8 * (reg >> 2) + 4 * hh;
      float gv = ksub ? o0[reg] : o1[reg];
      Oex[(size_t)(qsub * 32 + row) * 64 + gd] = gv;
    }
  }
  if (lane < 32) Lred[ksub * 64 + qsub * 32 + lane] = l_run;
  __syncthreads();
  {
    int d = ksub * 32 + l32;
#pragma unroll
    for (int reg = 0; reg < 16; reg++) {
      int row = (reg & 3) + 8 * (reg >> 2) + 4 * hh;
      int qg2 = qsub * 32 + row;
      float ltot = Lred[qg2] + Lred[64 + qg2];
      float keep = ksub ? o1[reg] : o0[reg];
      float v = (keep + Oex[(size_t)qg2 * 64 + d]) / ltot;
      O[(((size_t)(b * L) + qt * 64 + qg2) * NH + h) * DH + d] = __float2bfloat16(v);
    }
  }
}

extern "C" void kernel_launch(void* const* d_in, const int* in_sizes, int n_in,
                              void* d_out, int out_size, void* d_ws, size_t ws_size,
                              hipStream_t stream) {
  const float* x = (const float*)d_in[0];
  const float* pos = (const float*)d_in[1];
  const float* x_cross = (const float*)d_in[2];
  const float* pos_cross = (const float*)d_in[3];
  const float* sa_norm_scale = (const float*)d_in[4];
  const float* sa_wqkv = (const float*)d_in[5];
  const float* sa_scale = (const float*)d_in[6];
  const float* sa_wout = (const float*)d_in[7];
  const float* ca_norm_scale = (const float*)d_in[8];
  const float* ca_norm_cross_scale = (const float*)d_in[9];
  const float* ca_wq = (const float*)d_in[10];
  const float* ca_wkv = (const float*)d_in[11];
  const float* ca_scale = (const float*)d_in[12];
  const float* ca_wout = (const float*)d_in[13];
  const float* ff_norm_scale = (const float*)d_in[14];
  const float* ff_wup = (const float*)d_in[15];
  const float* ff_wdown = (const float*)d_in[16];
  float* out = (float*)d_out;

  float* ws = (float*)d_ws;
  const size_t S = (size_t)M_TOK * DM; // 3,145,728
  float* xbuf = ws; // S f32: running residual
  bf16* b16 = (bf16*)(ws + S);
  bf16* qkvb = b16;        // 3S: qkv (self) / caq + cakv (cross) / ffact (FF)
  bf16* qb = b16 + 3 * S;  // (BH, L, DH)
  bf16* kb = b16 + 4 * S;  // (BH, L, DH)
  bf16* vtb = b16 + 5 * S; // (BH, DH, L) key-permuted
  bf16* hb = b16 + 6 * S;
  bf16* hcb = b16 + 7 * S;
  bf16* obb = b16 + 8 * S; // attn out (B,L,NH,DH)
  bf16* wqkvb = b16 + 9 * S; // weight arena: 17*DM*DM contiguous, castall order
  bf16* woutb = wqkvb + (size_t)3 * DM * DM;
  bf16* wqb = woutb + (size_t)DM * DM;
  bf16* wkvb = wqb + (size_t)DM * DM;
  bf16* wout2b = wkvb + (size_t)2 * DM * DM;
  bf16* wupb = wout2b + (size_t)DM * DM;
  bf16* wdownb = wupb + (size_t)2 * DFF * DM;
  bf16* ffb = qkvb;

  const int ropeGrid = B * NH * L / 32; // 8 tokens/wave, 4 waves/block
  const int attnGrid = B * NH * (L / 64); // 768
  const int vtGrid = B * NH * (L / 64);   // 768
  const size_t DM2 = (size_t)DM * DM;
  const int castGrid = (int)((17 * DM2 / 4 + 255) / 256);

  k_castall<<<castGrid, 256, 0, stream>>>(sa_wqkv, sa_wout, ca_wq, ca_wkv, ca_wout, ff_wup,
                                          ff_wdown, wqkvb);

  // ---- merged prologue norms: self (x) + cross (x_cross) ----
  k_rmsnorm2<<<2 * M_TOK, 256, 0, stream>>>(x, sa_norm_scale, hb, x_cross, ca_norm_cross_scale,
                                            hcb);

  // ---- self attention ----
  k_gemm<128, 1><<<dim3(3 * DM / 128, M_TOK / 128), 256, 0, stream>>>(
      hb, wqkvb, nullptr, qkvb, nullptr, M_TOK, 3 * DM, DM);
  k_ropeqk<<<ropeGrid, 256, 0, stream>>>(qkvb, 3 * DM, 0, qkvb, 3 * DM, DM, pos, pos, sa_scale,
                                         qb, kb);
  k_vtrans<<<vtGrid, 256, 0, stream>>>(qkvb, 3 * DM, 2 * DM, vtb);
  k_attn_mfma<<<attnGrid, 256, 0, stream>>>(qb, kb, vtb, sa_scale, obb);
  k_gemm<64, 0><<<dim3(DM / 64, M_TOK / 128), 256, 0, stream>>>(
      obb, woutb, xbuf, nullptr, x, M_TOK, DM, DM); // xbuf = attn@wout + x

  // ---- cross attention ----
  k_rmsnorm<<<M_TOK, 256, 0, stream>>>(xbuf, ca_norm_scale, hb);
  k_gemm<64, 1><<<dim3(DM / 64, M_TOK / 128), 256, 0, stream>>>(
      hb, wqb, nullptr, qkvb, nullptr, M_TOK, DM, DM);
  k_gemm<128, 1><<<dim3(2 * DM / 128, M_TOK / 128), 256, 0, stream>>>(
      hcb, wkvb, nullptr, qkvb + S, nullptr, M_TOK, 2 * DM, DM);
  k_ropeqk<<<ropeGrid, 256, 0, stream>>>(qkvb, DM, 0, qkvb + S, 2 * DM, 0, pos, pos_cross,
                                         ca_scale, qb, kb);
  k_vtrans<<<vtGrid, 256, 0, stream>>>(qkvb + S, 2 * DM, DM, vtb);
  k_attn_mfma<<<attnGrid, 256, 0, stream>>>(qb, kb, vtb, ca_scale, obb);
  k_gemm<64, 0><<<dim3(DM / 64, M_TOK / 128), 256, 0, stream>>>(
      obb, wout2b, xbuf, nullptr, xbuf, M_TOK, DM, DM);

  // ---- feed-forward (fused up+SwiGLU, then down) ----
  k_rmsnorm<<<M_TOK, 256, 0, stream>>>(xbuf, ff_norm_scale, hb);
  k_ffup<<<dim3(DFF / 64, M_TOK / 128), 256, 0, stream>>>(hb, wupb, ffb);
  k_gemm<64, 0><<<dim3(DM / 64, M_TOK / 128), 256, 0, stream>>>(
      ffb, wdownb, out, nullptr, xbuf, M_TOK, DM, DFF);
}